// Round 21
// baseline (88.397 us; speedup 1.0000x reference)
//
#include <hip/hip_runtime.h>
#include <stdint.h>

#define BB 8
#define NN 2048
#define NC 80
#define MAXDET 512
#define WPR 32            // 64-bit words per row of the suppression matrix (2048/64)

// ---------------- ws layout (bytes) ----------------
// keysA  : uint64 [BB][NN]        @ 0        (131072)   unsorted keys
// keysB  : uint64 [BB][NN]        @ 131072   (131072)   sorted keys
// sboxes : float  [BB][NN][4]     @ 262144   (262144)
// sup    : uint64 [BB][NN][WPR]   @ 544768   (4194304)
// total ~4.52 MB

#define ORD_HALF 0xBF000000u   // orderable(0.5f)

// Kernel 0: conf = 1/(1+expf(-max_logit)) computed step-by-step in f32.
// key = orderable(conf) << 32 | (N-1-n): descending conf, ties -> smaller n.
__global__ __launch_bounds__(64) void k_conf(const float* __restrict__ cls,
                                             uint64_t* __restrict__ keys) {
    int gid = blockIdx.x * 64 + threadIdx.x;              // 0 .. BB*NN-1
    const float4* p = (const float4*)(cls + (size_t)gid * NC);
    float m = -3.0e38f;
#pragma unroll
    for (int i = 0; i < NC / 4; ++i) {
        float4 v = p[i];
        m = fmaxf(m, fmaxf(fmaxf(v.x, v.y), fmaxf(v.z, v.w)));
    }
    float e  = expf(-m);                 // f32
    float cf = 1.0f / (1.0f + e);        // f32 step-by-step
    uint32_t u = __float_as_uint(cf);
    u = (u & 0x80000000u) ? ~u : (u | 0x80000000u);       // monotone float->uint map
    int n = gid & (NN - 1);
    keys[gid] = ((uint64_t)u << 32) | (uint32_t)(NN - 1 - n);
}

// Kernel 1: parallel rank sort (exact permutation; keys distinct via index).
#define RCHUNK 128
__global__ __launch_bounds__(512) void k_rank(const uint64_t* __restrict__ keys_in,
                                              uint64_t* __restrict__ keys_out,
                                              const float* __restrict__ boxes,
                                              float* __restrict__ sboxes) {
    __shared__ uint64_t sk[NN];              // 16 KB
    __shared__ uint16_t part[4][RCHUNK];     // 1 KB
    int b = blockIdx.y, t = threadIdx.x;
    const uint64_t* kin = keys_in + (size_t)b * NN;
#pragma unroll
    for (int j = 0; j < NN / 512; ++j)
        sk[t + j * 512] = kin[t + j * 512];
    __syncthreads();
    int sub = t >> 7;                        // scan quarter 0..3 (uniform per wave)
    int el  = t & (RCHUNK - 1);              // element within chunk
    int e   = blockIdx.x * RCHUNK + el;
    uint64_t mykey = sk[e];
    int base = sub * (NN / 4);
    int r = 0;
    for (int mm = 0; mm < NN / 4; ++mm)
        r += (sk[base + mm] > mykey) ? 1 : 0;
    part[sub][el] = (uint16_t)r;
    __syncthreads();
    if (t < RCHUNK) {
        int rank = part[0][t] + part[1][t] + part[2][t] + part[3][t];
        keys_out[(size_t)b * NN + rank] = mykey;
        int orig = (NN - 1) - (int)(mykey & 0xFFFFFFFFull);
        ((float4*)sboxes)[(size_t)b * NN + rank] =
            ((const float4*)boxes)[(size_t)b * NN + orig];
    }
}

// Kernel 2: suppression bit matrix. Block = 64-row x 256-col tile.
// Bit c of word gw of row r: IoU(r, col) > 0.5 && col > r.
__global__ void k_sup(const float* __restrict__ sboxes, uint64_t* __restrict__ sup) {
#pragma clang fp contract(off)
    __shared__ float cy1[256], cx1[256], cy2[256], cx2[256], car[256];
    __shared__ float ry1[64], rx1[64], ry2[64], rx2[64], rar[64];
    int rt = blockIdx.x, ct = blockIdx.y, b = blockIdx.z;
    int t = threadIdx.x;
    int col0 = ct << 8, row0 = rt << 6;
    {
        float4 bx = ((const float4*)sboxes)[(size_t)b * NN + col0 + t];
        cy1[t] = bx.x; cx1[t] = bx.y; cy2[t] = bx.z; cx2[t] = bx.w;
        car[t] = (bx.z - bx.x) * (bx.w - bx.y);
        if (t < 64) {
            float4 rb = ((const float4*)sboxes)[(size_t)b * NN + row0 + t];
            ry1[t] = rb.x; rx1[t] = rb.y; ry2[t] = rb.z; rx2[t] = rb.w;
            rar[t] = (rb.z - rb.x) * (rb.w - rb.y);
        }
    }
    __syncthreads();
    int lr = t & 63, lg = t >> 6;
    int r = row0 + lr;
    int gw = (ct << 2) + lg;
    int cbase = gw << 6;
    uint64_t w = 0;
    if (cbase + 63 > r) {                  // tile not entirely at/below diagonal
        float y1 = ry1[lr], x1 = rx1[lr], y2 = ry2[lr], x2 = rx2[lr], ar = rar[lr];
        int lcb = lg << 6;
        for (int c = 0; c < 64; ++c) {
            int lc = lcb + c;
            float ih = fmaxf(fminf(y2, cy2[lc]) - fmaxf(y1, cy1[lc]), 0.0f);
            float iw = fmaxf(fminf(x2, cx2[lc]) - fmaxf(x1, cx1[lc]), 0.0f);
            float inter = ih * iw;
            float uni = (ar + car[lc]) - inter;
            float iou = inter / fmaxf(uni, 1e-9f);
            if ((iou > 0.5f) & ((cbase + c) > r)) w |= (1ull << c);
        }
    }
    sup[((size_t)b * NN + r) * WPR + gw] = w;
}

// Kernel 3: greedy scan (r16 proven: 5-wave structure + branchless SALU chain
// + transposed diag buffer) with the SOFTMAX EPILOGUE FUSED IN: kept indices
// go to LDS kidxS; after compaction, row-per-thread softmax (2 slots/thread,
// 20x float4 gather + 3-pass max/exp/scale in registers) writes out_cls.
// Removes the separate k_softmax launch and the kidx/kcount globals.
#define NMS_THREADS 320
__global__ __launch_bounds__(NMS_THREADS) void k_nms(const uint64_t* __restrict__ keys,
                                                     const float* __restrict__ sboxes,
                                                     const uint64_t* __restrict__ sup,
                                                     const float* __restrict__ cls,
                                                     float* __restrict__ out_box,
                                                     float* __restrict__ out_conf,
                                                     float* __restrict__ out_cls) {
    __shared__ uint64_t buf[2][64 * WPR];   // 2 x 16 KB
    __shared__ uint64_t dgT[2][64];         // transposed diagonal words
    __shared__ uint8_t  val[NN];            // 2 KB
    __shared__ uint64_t kmaskS[WPR];
    __shared__ int pfx[WPR];
    __shared__ int kidxS[MAXDET];           // 2 KB kept original indices
    __shared__ int s_kc;
    __shared__ int s_done;
    int b = blockIdx.x, t = threadIdx.x;
    const uint64_t* supb = sup + (size_t)b * NN * WPR;
    const uint64_t* keyb = keys + (size_t)b * NN;

    for (int i = t; i < NN; i += NMS_THREADS)
        val[i] = (uint8_t)((uint32_t)(keyb[i] >> 32) > ORD_HALF);  // conf > 0.5f
    if (t < WPR) kmaskS[t] = 0;
    if (t == 0) s_done = 0;
    for (int e = t; e < 64 * WPR / 2; e += NMS_THREADS) {  // stage group 0 (16B units)
        ulonglong2 v = ((const ulonglong2*)supb)[e];
        ((ulonglong2*)buf[0])[e] = v;
        if ((e & 15) == 0) dgT[0][e >> 4] = v.x;           // word 0 = group-0 diag
    }
    __syncthreads();

    int wave = t >> 6;
    uint64_t kb = 0;      // lane l (wave 0, l<32) owns removed-word l
    int cnt = 0;
    if (t < 32) {
        uint64_t vm = 0;
#pragma unroll
        for (int c = 0; c < 64; ++c)
            vm |= ((uint64_t)val[(t << 6) | c]) << c;
        kb = ~vm;         // invalid = pre-removed
    }
    int l2 = t & 31, half = (t >> 5) & 1;

    for (int g = 0; g < WPR; ++g) {
        if (wave > 0) {
            if (g + 1 < WPR) {                      // stage next group: 1024 x 16B
                const ulonglong2* src = (const ulonglong2*)(supb + (size_t)(g + 1) * 64 * WPR);
                ulonglong2* dst = (ulonglong2*)buf[(g + 1) & 1];
                int idx = t - 64;                   // 0..255
                ulonglong2 r0 = src[idx];
                ulonglong2 r1 = src[idx + 256];
                ulonglong2 r2 = src[idx + 512];
                ulonglong2 r3 = src[idx + 768];
                dst[idx]       = r0;
                dst[idx + 256] = r1;
                dst[idx + 512] = r2;
                dst[idx + 768] = r3;
                // extract diagonal word g+1 (16B pair (g+1)>>1, half (g+1)&1)
                if ((idx & 15) == ((g + 1) >> 1)) {
                    int r = idx >> 4;               // rows r, r+16, r+32, r+48
                    int hi = (g + 1) & 1;
                    uint64_t* dT = dgT[(g + 1) & 1];
                    dT[r]      = hi ? r0.y : r0.x;
                    dT[r + 16] = hi ? r1.y : r1.x;
                    dT[r + 32] = hi ? r2.y : r2.x;
                    dT[r + 48] = hi ? r3.y : r3.x;
                }
            }
        } else {
            const uint64_t* bufc = buf[g & 1];
            uint64_t diag = dgT[g & 1][t];              // conflict-free diag read
            uint32_t dlo = (uint32_t)diag, dhi = (uint32_t)(diag >> 32);
            uint64_t rwv = __shfl(kb, g);
            uint32_t rw_lo = __builtin_amdgcn_readfirstlane((uint32_t)rwv);
            uint32_t rw_hi = __builtin_amdgcn_readfirstlane((uint32_t)(rwv >> 32));
            uint32_t gm_lo = 0, gm_hi = 0;
#pragma unroll
            for (int c = 0; c < 32; ++c) {              // bits 0..31, branchless
                uint32_t rlo = __builtin_amdgcn_readlane(dlo, c);
                uint32_t rhi = __builtin_amdgcn_readlane(dhi, c);
                uint32_t keep = (~(rw_lo >> c)) & 1u;
                uint32_t msk  = 0u - keep;
                rw_lo |= rlo & msk;
                rw_hi |= rhi & msk;
                gm_lo |= keep << c;
            }
#pragma unroll
            for (int c = 0; c < 32; ++c) {              // bits 32..63, branchless
                uint32_t rlo = __builtin_amdgcn_readlane(dlo, c + 32);
                uint32_t rhi = __builtin_amdgcn_readlane(dhi, c + 32);
                uint32_t keep = (~(rw_hi >> c)) & 1u;
                uint32_t msk  = 0u - keep;
                rw_lo |= rlo & msk;
                rw_hi |= rhi & msk;
                gm_hi |= keep << c;
            }
            uint64_t gm = ((uint64_t)gm_hi << 32) | gm_lo;
            // phase 2: cross-group suppression from LDS (half-split, branchless)
            uint32_t gmh = half ? gm_hi : gm_lo;
            const uint64_t* rowp = bufc + ((half << 5) * WPR + l2);
            uint64_t acc = 0;
#pragma unroll
            for (int j = 0; j < 32; ++j) {
                uint64_t row = rowp[(size_t)j * WPR];
                acc |= (((gmh >> j) & 1u) ? row : 0ull);
            }
            acc |= __shfl(acc, t ^ 32);             // combine halves
            if (t < 32) kb |= acc;
            if (t == g) kmaskS[g] = gm;
            cnt += __popcll(gm);                    // uniform in wave 0
            if (cnt >= MAXDET) s_done = 1;
        }
        __syncthreads();                            // staging done + flag visible
        if (s_done) break;
    }

    if (t == 0) {
        int s = 0;
        for (int w2 = 0; w2 < WPR; ++w2) { pfx[w2] = s; s += __popcll(kmaskS[w2]); }
        s_kc = (s < MAXDET) ? s : MAXDET;
    }
    __syncthreads();
    for (int i = t; i < NN; i += NMS_THREADS) {
        uint64_t m = kmaskS[i >> 6];
        if ((m >> (i & 63)) & 1ull) {
            int rank = pfx[i >> 6] + __popcll(m & ((1ull << (i & 63)) - 1ull));
            if (rank < MAXDET) {
                ((float4*)out_box)[(size_t)b * MAXDET + rank] =
                    ((const float4*)sboxes)[(size_t)b * NN + i];
                uint64_t kk = keyb[i];
                uint32_t u = (uint32_t)(kk >> 32);
                float cf = (u & 0x80000000u) ? __uint_as_float(u ^ 0x80000000u)
                                             : __uint_as_float(~u);
                out_conf[(size_t)b * MAXDET + rank] = cf;
                kidxS[rank] = (NN - 1) - (int)(kk & 0xFFFFFFFFull);
            }
        }
    }
    for (int k = s_kc + t; k < MAXDET; k += NMS_THREADS) {
        ((float4*)out_box)[(size_t)b * MAXDET + k] = make_float4(0.f, 0.f, 0.f, 0.f);
        out_conf[(size_t)b * MAXDET + k] = 0.0f;
    }
    __syncthreads();   // kidxS + s_kc visible

    // ---- fused softmax epilogue: row-per-thread over the 512 output slots ----
    int kc = s_kc;
    for (int k = t; k < MAXDET; k += NMS_THREADS) {
        float4* dst = (float4*)(out_cls + ((size_t)b * MAXDET + k) * NC);
        if (k < kc) {
            int n = kidxS[k];
            const float4* src = (const float4*)(cls + ((size_t)b * NN + n) * NC);
            float4 v[NC / 4];                      // 20 x float4, constant-indexed
#pragma unroll
            for (int q = 0; q < NC / 4; ++q) v[q] = src[q];
            float mx = -3.0e38f;
#pragma unroll
            for (int q = 0; q < NC / 4; ++q)
                mx = fmaxf(mx, fmaxf(fmaxf(v[q].x, v[q].y), fmaxf(v[q].z, v[q].w)));
            float s = 0.0f;
#pragma unroll
            for (int q = 0; q < NC / 4; ++q) {
                v[q].x = expf(v[q].x - mx); s += v[q].x;
                v[q].y = expf(v[q].y - mx); s += v[q].y;
                v[q].z = expf(v[q].z - mx); s += v[q].z;
                v[q].w = expf(v[q].w - mx); s += v[q].w;
            }
            float inv = 1.0f / s;
#pragma unroll
            for (int q = 0; q < NC / 4; ++q) {
                v[q].x *= inv; v[q].y *= inv; v[q].z *= inv; v[q].w *= inv;
                dst[q] = v[q];
            }
        } else {
            float4 z = make_float4(0.f, 0.f, 0.f, 0.f);
#pragma unroll
            for (int q = 0; q < NC / 4; ++q) dst[q] = z;
        }
    }
}

extern "C" void kernel_launch(void* const* d_in, const int* in_sizes, int n_in,
                              void* d_out, int out_size, void* d_ws, size_t ws_size,
                              hipStream_t stream) {
    const float* boxes = (const float*)d_in[0];   // [8][2048][4]
    const float* cls   = (const float*)d_in[1];   // [8][2048][80]
    float* out      = (float*)d_out;
    float* out_box  = out;                          // [8][512][4]
    float* out_cls  = out + BB * MAXDET * 4;        // [8][512][80]
    float* out_conf = out + BB * MAXDET * (4 + NC); // [8][512]

    char* ws = (char*)d_ws;
    uint64_t* keysA  = (uint64_t*)(ws + 0);
    uint64_t* keysB  = (uint64_t*)(ws + 131072);
    float*    sboxes = (float*)(ws + 262144);
    uint64_t* sup    = (uint64_t*)(ws + 544768);

    k_conf<<<(BB * NN) / 64, 64, 0, stream>>>(cls, keysA);
    k_rank<<<dim3(NN / RCHUNK, BB), 512, 0, stream>>>(keysA, keysB, boxes, sboxes);
    k_sup<<<dim3(NN / 64, NN / 256, BB), 256, 0, stream>>>(sboxes, sup);
    k_nms<<<BB, NMS_THREADS, 0, stream>>>(keysB, sboxes, sup, cls,
                                          out_box, out_conf, out_cls);
}

// Round 22
// 73.907 us; speedup vs baseline: 1.1960x; 1.1960x over previous
//
#include <hip/hip_runtime.h>
#include <stdint.h>

#define BB 8
#define NN 2048
#define NC 80
#define MAXDET 512
#define WPR 32            // 64-bit words per row of the suppression matrix (2048/64)

// ---------------- ws layout (bytes) ----------------
// keysA  : uint64 [BB][NN]        @ 0        (131072)   unsorted keys
// keysB  : uint64 [BB][NN]        @ 131072   (131072)   sorted keys
// sboxes : float  [BB][NN][4]     @ 262144   (262144)
// kidx   : int32  [BB][MAXDET]    @ 524288   (16384)
// kcount : int32  [BB]            @ 540672   (128 pad)
// sup    : uint64 [BB][NN][WPR]   @ 544768   (4194304)
// total ~4.52 MB

#define ORD_HALF 0xBF000000u   // orderable(0.5f)

// Kernel 0: conf = 1/(1+expf(-max_logit)) computed step-by-step in f32.
// key = orderable(conf) << 32 | (N-1-n): descending conf, ties -> smaller n.
__global__ __launch_bounds__(64) void k_conf(const float* __restrict__ cls,
                                             uint64_t* __restrict__ keys) {
    int gid = blockIdx.x * 64 + threadIdx.x;              // 0 .. BB*NN-1
    const float4* p = (const float4*)(cls + (size_t)gid * NC);
    float m = -3.0e38f;
#pragma unroll
    for (int i = 0; i < NC / 4; ++i) {
        float4 v = p[i];
        m = fmaxf(m, fmaxf(fmaxf(v.x, v.y), fmaxf(v.z, v.w)));
    }
    float e  = expf(-m);                 // f32
    float cf = 1.0f / (1.0f + e);        // f32 step-by-step
    uint32_t u = __float_as_uint(cf);
    u = (u & 0x80000000u) ? ~u : (u | 0x80000000u);       // monotone float->uint map
    int n = gid & (NN - 1);
    keys[gid] = ((uint64_t)u << 32) | (uint32_t)(NN - 1 - n);
}

// Kernel 1: parallel rank sort (exact permutation; keys distinct via index).
#define RCHUNK 128
__global__ __launch_bounds__(512) void k_rank(const uint64_t* __restrict__ keys_in,
                                              uint64_t* __restrict__ keys_out,
                                              const float* __restrict__ boxes,
                                              float* __restrict__ sboxes) {
    __shared__ uint64_t sk[NN];              // 16 KB
    __shared__ uint16_t part[4][RCHUNK];     // 1 KB
    int b = blockIdx.y, t = threadIdx.x;
    const uint64_t* kin = keys_in + (size_t)b * NN;
#pragma unroll
    for (int j = 0; j < NN / 512; ++j)
        sk[t + j * 512] = kin[t + j * 512];
    __syncthreads();
    int sub = t >> 7;                        // scan quarter 0..3 (uniform per wave)
    int el  = t & (RCHUNK - 1);              // element within chunk
    int e   = blockIdx.x * RCHUNK + el;
    uint64_t mykey = sk[e];
    int base = sub * (NN / 4);
    int r = 0;
    for (int mm = 0; mm < NN / 4; ++mm)
        r += (sk[base + mm] > mykey) ? 1 : 0;
    part[sub][el] = (uint16_t)r;
    __syncthreads();
    if (t < RCHUNK) {
        int rank = part[0][t] + part[1][t] + part[2][t] + part[3][t];
        keys_out[(size_t)b * NN + rank] = mykey;
        int orig = (NN - 1) - (int)(mykey & 0xFFFFFFFFull);
        ((float4*)sboxes)[(size_t)b * NN + rank] =
            ((const float4*)boxes)[(size_t)b * NN + orig];
    }
}

// Kernel 2: suppression bit matrix. Block = 64-row x 256-col tile.
// Bit c of word gw of row r: IoU(r, col) > 0.5 && col > r.
// Optimized: (a) packed float4 column boxes (1 b128 + 1 b32 broadcast/iter
// instead of 5 scalar LDS reads); (b) division-free threshold test —
// iou > 0.5 <=> inter > 0.5*M (0.5*M exact); lanes in the conservative
// tie-window |inter-hm| <= 1e-6*hm re-evaluate with the ORIGINAL division
// expression (rare, __any-guarded) so verdicts are bit-identical;
// (c) triangular condition applied once as an end mask.
__global__ void k_sup(const float* __restrict__ sboxes, uint64_t* __restrict__ sup) {
#pragma clang fp contract(off)
    __shared__ float4 cbox[256];
    __shared__ float  carS[256];
    __shared__ float ry1[64], rx1[64], ry2[64], rx2[64], rar[64];
    int rt = blockIdx.x, ct = blockIdx.y, b = blockIdx.z;
    int t = threadIdx.x;
    int col0 = ct << 8, row0 = rt << 6;
    {
        float4 bx = ((const float4*)sboxes)[(size_t)b * NN + col0 + t];
        cbox[t] = bx;
        carS[t] = (bx.z - bx.x) * (bx.w - bx.y);
        if (t < 64) {
            float4 rb = ((const float4*)sboxes)[(size_t)b * NN + row0 + t];
            ry1[t] = rb.x; rx1[t] = rb.y; ry2[t] = rb.z; rx2[t] = rb.w;
            rar[t] = (rb.z - rb.x) * (rb.w - rb.y);
        }
    }
    __syncthreads();
    int lr = t & 63, lg = t >> 6;
    int r = row0 + lr;
    int gw = (ct << 2) + lg;
    int cbase = gw << 6;
    uint64_t w = 0;
    if (cbase + 63 > r) {                  // tile not entirely at/below diagonal
        float y1 = ry1[lr], x1 = rx1[lr], y2 = ry2[lr], x2 = rx2[lr], ar = rar[lr];
        int lcb = lg << 6;
        for (int c = 0; c < 64; ++c) {
            float4 cb = cbox[lcb + c];     // broadcast (uniform addr per wave)
            float ca  = carS[lcb + c];
            float ih = fmaxf(fminf(y2, cb.z) - fmaxf(y1, cb.x), 0.0f);
            float iw = fmaxf(fminf(x2, cb.w) - fmaxf(x1, cb.y), 0.0f);
            float inter = ih * iw;
            float uni = (ar + ca) - inter;
            float M  = fmaxf(uni, 1e-9f);
            float hm = 0.5f * M;           // exact (power-of-2 scale)
            bool s = inter > hm;           // == (iou > 0.5) outside tie window
            bool near = fabsf(inter - hm) <= 1e-6f * hm;
            if (__builtin_expect((bool)__any(near), 0)) {
                float iou = inter / M;     // original expression, exact verdict
                s = iou > 0.5f;
            }
            w |= ((uint64_t)s) << c;
        }
        int tc = r - cbase;                // cols c<=tc are col<=row: disallowed
        uint64_t allow = (tc < 0) ? ~0ull
                       : ((tc >= 63) ? 0ull : (~0ull << (tc + 1)));
        w &= allow;
    }
    sup[((size_t)b * NN + r) * WPR + gw] = w;
}

// Kernel 3: greedy scan, 5-wave structure + branchless SALU chain +
// transposed diag buffer (r14/r16, ref-check passed; unchanged).
#define NMS_THREADS 320
__global__ __launch_bounds__(NMS_THREADS) void k_nms(const uint64_t* __restrict__ keys,
                                                     const float* __restrict__ sboxes,
                                                     const uint64_t* __restrict__ sup,
                                                     int* __restrict__ kidx,
                                                     int* __restrict__ kcount,
                                                     float* __restrict__ out_box,
                                                     float* __restrict__ out_conf) {
    __shared__ uint64_t buf[2][64 * WPR];   // 2 x 16 KB
    __shared__ uint64_t dgT[2][64];         // transposed diagonal words
    __shared__ uint8_t  val[NN];            // 2 KB
    __shared__ uint64_t kmaskS[WPR];
    __shared__ int pfx[WPR];
    __shared__ int s_kc;
    __shared__ int s_done;
    int b = blockIdx.x, t = threadIdx.x;
    const uint64_t* supb = sup + (size_t)b * NN * WPR;
    const uint64_t* keyb = keys + (size_t)b * NN;

    for (int i = t; i < NN; i += NMS_THREADS)
        val[i] = (uint8_t)((uint32_t)(keyb[i] >> 32) > ORD_HALF);  // conf > 0.5f
    if (t < WPR) kmaskS[t] = 0;
    if (t == 0) s_done = 0;
    for (int e = t; e < 64 * WPR / 2; e += NMS_THREADS) {  // stage group 0 (16B units)
        ulonglong2 v = ((const ulonglong2*)supb)[e];
        ((ulonglong2*)buf[0])[e] = v;
        if ((e & 15) == 0) dgT[0][e >> 4] = v.x;           // word 0 = group-0 diag
    }
    __syncthreads();

    int wave = t >> 6;
    uint64_t kb = 0;      // lane l (wave 0, l<32) owns removed-word l
    int cnt = 0;
    if (t < 32) {
        uint64_t vm = 0;
#pragma unroll
        for (int c = 0; c < 64; ++c)
            vm |= ((uint64_t)val[(t << 6) | c]) << c;
        kb = ~vm;         // invalid = pre-removed
    }
    int l2 = t & 31, half = (t >> 5) & 1;

    for (int g = 0; g < WPR; ++g) {
        if (wave > 0) {
            if (g + 1 < WPR) {                      // stage next group: 1024 x 16B
                const ulonglong2* src = (const ulonglong2*)(supb + (size_t)(g + 1) * 64 * WPR);
                ulonglong2* dst = (ulonglong2*)buf[(g + 1) & 1];
                int idx = t - 64;                   // 0..255
                ulonglong2 r0 = src[idx];
                ulonglong2 r1 = src[idx + 256];
                ulonglong2 r2 = src[idx + 512];
                ulonglong2 r3 = src[idx + 768];
                dst[idx]       = r0;
                dst[idx + 256] = r1;
                dst[idx + 512] = r2;
                dst[idx + 768] = r3;
                // extract diagonal word g+1 (16B pair (g+1)>>1, half (g+1)&1)
                if ((idx & 15) == ((g + 1) >> 1)) {
                    int r = idx >> 4;               // rows r, r+16, r+32, r+48
                    int hi = (g + 1) & 1;
                    uint64_t* dT = dgT[(g + 1) & 1];
                    dT[r]      = hi ? r0.y : r0.x;
                    dT[r + 16] = hi ? r1.y : r1.x;
                    dT[r + 32] = hi ? r2.y : r2.x;
                    dT[r + 48] = hi ? r3.y : r3.x;
                }
            }
        } else {
            const uint64_t* bufc = buf[g & 1];
            uint64_t diag = dgT[g & 1][t];              // conflict-free diag read
            uint32_t dlo = (uint32_t)diag, dhi = (uint32_t)(diag >> 32);
            uint64_t rwv = __shfl(kb, g);
            uint32_t rw_lo = __builtin_amdgcn_readfirstlane((uint32_t)rwv);
            uint32_t rw_hi = __builtin_amdgcn_readfirstlane((uint32_t)(rwv >> 32));
            uint32_t gm_lo = 0, gm_hi = 0;
#pragma unroll
            for (int c = 0; c < 32; ++c) {              // bits 0..31, branchless
                uint32_t rlo = __builtin_amdgcn_readlane(dlo, c);
                uint32_t rhi = __builtin_amdgcn_readlane(dhi, c);
                uint32_t keep = (~(rw_lo >> c)) & 1u;
                uint32_t msk  = 0u - keep;
                rw_lo |= rlo & msk;
                rw_hi |= rhi & msk;
                gm_lo |= keep << c;
            }
#pragma unroll
            for (int c = 0; c < 32; ++c) {              // bits 32..63, branchless
                uint32_t rlo = __builtin_amdgcn_readlane(dlo, c + 32);
                uint32_t rhi = __builtin_amdgcn_readlane(dhi, c + 32);
                uint32_t keep = (~(rw_hi >> c)) & 1u;
                uint32_t msk  = 0u - keep;
                rw_lo |= rlo & msk;
                rw_hi |= rhi & msk;
                gm_hi |= keep << c;
            }
            uint64_t gm = ((uint64_t)gm_hi << 32) | gm_lo;
            // phase 2: cross-group suppression from LDS (half-split, branchless)
            uint32_t gmh = half ? gm_hi : gm_lo;
            const uint64_t* rowp = bufc + ((half << 5) * WPR + l2);
            uint64_t acc = 0;
#pragma unroll
            for (int j = 0; j < 32; ++j) {
                uint64_t row = rowp[(size_t)j * WPR];
                acc |= (((gmh >> j) & 1u) ? row : 0ull);
            }
            acc |= __shfl(acc, t ^ 32);             // combine halves
            if (t < 32) kb |= acc;
            if (t == g) kmaskS[g] = gm;
            cnt += __popcll(gm);                    // uniform in wave 0
            if (cnt >= MAXDET) s_done = 1;
        }
        __syncthreads();                            // staging done + flag visible
        if (s_done) break;
    }

    if (t == 0) {
        int s = 0;
        for (int w2 = 0; w2 < WPR; ++w2) { pfx[w2] = s; s += __popcll(kmaskS[w2]); }
        s_kc = (s < MAXDET) ? s : MAXDET;
        kcount[b] = s_kc;
    }
    __syncthreads();
    for (int i = t; i < NN; i += NMS_THREADS) {
        uint64_t m = kmaskS[i >> 6];
        if ((m >> (i & 63)) & 1ull) {
            int rank = pfx[i >> 6] + __popcll(m & ((1ull << (i & 63)) - 1ull));
            if (rank < MAXDET) {
                ((float4*)out_box)[(size_t)b * MAXDET + rank] =
                    ((const float4*)sboxes)[(size_t)b * NN + i];
                uint64_t kk = keyb[i];
                uint32_t u = (uint32_t)(kk >> 32);
                float cf = (u & 0x80000000u) ? __uint_as_float(u ^ 0x80000000u)
                                             : __uint_as_float(~u);
                out_conf[(size_t)b * MAXDET + rank] = cf;
                kidx[b * MAXDET + rank] = (NN - 1) - (int)(kk & 0xFFFFFFFFull);
            }
        }
    }
    for (int k = s_kc + t; k < MAXDET; k += NMS_THREADS) {
        ((float4*)out_box)[(size_t)b * MAXDET + k] = make_float4(0.f, 0.f, 0.f, 0.f);
        out_conf[(size_t)b * MAXDET + k] = 0.0f;
    }
}

// Kernel 4: softmax gather for kept rows; zero-fill the rest. One wave per slot.
__global__ void k_softmax(const float* __restrict__ cls, const int* __restrict__ kidx,
                          const int* __restrict__ kcount, float* __restrict__ out_cls) {
    int k = blockIdx.x, b = blockIdx.y, lane = threadIdx.x;  // 64 threads
    float* dst = out_cls + ((size_t)b * MAXDET + k) * NC;
    if (k >= kcount[b]) {
        dst[lane] = 0.0f;
        if (lane < NC - 64) dst[64 + lane] = 0.0f;
        return;
    }
    int n = kidx[b * MAXDET + k];
    const float* src = cls + ((size_t)b * NN + n) * NC;
    float x0 = src[lane];
    float x1 = (lane < NC - 64) ? src[64 + lane] : -3.0e38f;
    float m = fmaxf(x0, x1);
    for (int o = 32; o > 0; o >>= 1) m = fmaxf(m, __shfl_xor(m, o));
    float e0 = expf(x0 - m);
    float e1 = (lane < NC - 64) ? expf(x1 - m) : 0.0f;
    float s = e0 + e1;
    for (int o = 32; o > 0; o >>= 1) s += __shfl_xor(s, o);
    dst[lane] = e0 / s;
    if (lane < NC - 64) dst[64 + lane] = e1 / s;
}

extern "C" void kernel_launch(void* const* d_in, const int* in_sizes, int n_in,
                              void* d_out, int out_size, void* d_ws, size_t ws_size,
                              hipStream_t stream) {
    const float* boxes = (const float*)d_in[0];   // [8][2048][4]
    const float* cls   = (const float*)d_in[1];   // [8][2048][80]
    float* out      = (float*)d_out;
    float* out_box  = out;                          // [8][512][4]
    float* out_cls  = out + BB * MAXDET * 4;        // [8][512][80]
    float* out_conf = out + BB * MAXDET * (4 + NC); // [8][512]

    char* ws = (char*)d_ws;
    uint64_t* keysA  = (uint64_t*)(ws + 0);
    uint64_t* keysB  = (uint64_t*)(ws + 131072);
    float*    sboxes = (float*)(ws + 262144);
    int*      kidx   = (int*)(ws + 524288);
    int*      kcount = (int*)(ws + 540672);
    uint64_t* sup    = (uint64_t*)(ws + 544768);

    k_conf<<<(BB * NN) / 64, 64, 0, stream>>>(cls, keysA);
    k_rank<<<dim3(NN / RCHUNK, BB), 512, 0, stream>>>(keysA, keysB, boxes, sboxes);
    k_sup<<<dim3(NN / 64, NN / 256, BB), 256, 0, stream>>>(sboxes, sup);
    k_nms<<<BB, NMS_THREADS, 0, stream>>>(keysB, sboxes, sup, kidx, kcount, out_box, out_conf);
    k_softmax<<<dim3(MAXDET, BB), 64, 0, stream>>>(cls, kidx, kcount, out_cls);
}